// Round 1
// baseline (11776.101 us; speedup 1.0000x reference)
//
#include <hip/hip_runtime.h>

typedef __attribute__((ext_vector_type(8))) short short8;
typedef __attribute__((ext_vector_type(4))) float f32x4;
typedef unsigned short u16;

#define TP   1022      // conv output length = T-2
#define NWG  64        // workgroups in persistent LSTM kernel

// ws layout (byte offsets, all 256-aligned)
#define OFF_WPACK   0            // 2048*576*2   = 2359296
#define OFF_SEQ     2359296      // 1022*64*64*2 = 8372224
#define OFF_RNORM   10731520     // 64*1024*4    = 262144
#define OFF_BIAS    10993664     // 2048*4       = 8192
#define OFF_H0      11001856     // 64*512*2     = 65536
#define OFF_H1      11067392     // 64*512*2     = 65536
#define OFF_HFIN    11132928     // 64*512*4     = 131072
#define OFF_BAR     11264000     // barrier: counter @ +0, flag @ +128B

__device__ inline u16 f2bf(float x) {
  union { float f; unsigned u; } un; un.f = x;
  unsigned r = un.u + 0x7fffu + ((un.u >> 16) & 1u);  // RNE
  return (u16)(r >> 16);
}
__device__ inline float sigmoidf_(float x) { return 1.f / (1.f + __expf(-x)); }
__device__ inline float tanhf_(float x)    { return 2.f / (1.f + __expf(-2.f * x)) - 1.f; }

// ---- init: zero h buffers + barrier, build packed bias (b_ih+b_hh in packed n-order)
__global__ void k_init(const float* __restrict__ b_ih, const float* __restrict__ b_hh,
                       float* __restrict__ biasp, unsigned* __restrict__ hzero,
                       unsigned* __restrict__ bar) {
  int tid = blockIdx.x * 256 + threadIdx.x;
  if (tid < 32768) hzero[tid] = 0u;                 // both h bufs (131072 B)
  if (tid < 2048) {
    int j = tid >> 2, g = tid & 3;
    int row = g * 512 + j;
    biasp[tid] = b_ih[row] + b_hh[row];
  }
  if (tid < 64) bar[tid] = 0u;
}

// ---- pack W = [w_ih ; w_hh] (2048 x 576) transposed into MFMA B-fragment order, bf16.
// packed column n = 4*j + g  (gate-interleaved).  element layout per (ntile,ktile):
// lane holds col n0+(lane&15), k = k0 + (lane>>4)*8 + i, 8 contiguous bf16 per lane.
__global__ void k_pack(const float* __restrict__ w_ih, const float* __restrict__ w_hh,
                       u16* __restrict__ wp) {
  int idx = blockIdx.x * 256 + threadIdx.x;        // < 128*18*512 = 1179648
  int nt = idx / 9216;
  int rem = idx - nt * 9216;
  int kt = rem / 512;
  int rem2 = rem - kt * 512;
  int lane = rem2 >> 3, i = rem2 & 7;
  int n = nt * 16 + (lane & 15);
  int k = kt * 32 + (lane >> 4) * 8 + i;
  int j = n >> 2, g = n & 3;
  int row = g * 512 + j;
  float v = (k < 64) ? w_ih[row * 64 + k] : w_hh[row * 512 + (k - 64)];
  wp[idx] = f2bf(v);
}

// ---- L2 row norms: one wave per (b,t) row of 128
__global__ void k_norm(const float* __restrict__ inX, float* __restrict__ rnorm) {
  int row = blockIdx.x * 4 + (threadIdx.x >> 6);   // b*1024 + t
  int lane = threadIdx.x & 63;
  const float2 v = *reinterpret_cast<const float2*>(inX + (size_t)row * 128 + lane * 2);
  float s = v.x * v.x + v.y * v.y;
  #pragma unroll
  for (int d = 1; d < 64; d <<= 1) s += __shfl_xor(s, d);
  if (lane == 0) rnorm[row] = 1.f / fmaxf(sqrtf(s), 1e-12f);
}

// ---- normalize + conv1d(k=3, VALID) + relu -> seq[t][b][oc] bf16
__global__ __launch_bounds__(256) void k_conv(const float* __restrict__ inX,
                                              const float* __restrict__ rnorm,
                                              const float* __restrict__ conv_w,
                                              const float* __restrict__ conv_b,
                                              u16* __restrict__ seq) {
  __shared__ float xn[6][128];
  int b = blockIdx.y;
  int t0 = blockIdx.x * 4;
  int tid = threadIdx.x;
  for (int e = tid; e < 768; e += 256) {
    int ri = e >> 7, col = e & 127;
    int t = t0 + ri;
    if (t < 1024) xn[ri][col] = inX[((size_t)b * 1024 + t) * 128 + col] * rnorm[b * 1024 + t];
  }
  __syncthreads();
  int oc = tid & 63, ty = tid >> 6;
  int t = t0 + ty;
  if (t < TP) {
    const float* wr = conv_w + oc * 384;           // (OC, IN, 3) row-major
    float s = conv_b[oc];
    #pragma unroll 4
    for (int i = 0; i < 128; ++i) {
      s += wr[i * 3 + 0] * xn[ty + 0][i]
         + wr[i * 3 + 1] * xn[ty + 1][i]
         + wr[i * 3 + 2] * xn[ty + 2][i];
    }
    s = fmaxf(s, 0.f);
    seq[((size_t)t * 64 + b) * 64 + oc] = f2bf(s);
  }
}

// ---- persistent LSTM: 64 WGs x 256 thr; wave handles 1 n-tile (16 gate cols = 4 units)
// x 2 m-tiles (32 batches). c-state lives in registers across all 1022 steps.
__global__ __launch_bounds__(256, 1) void k_lstm(const u16* __restrict__ seq,
                                                 const u16* __restrict__ wp,
                                                 const float* __restrict__ biasp,
                                                 u16* h0buf, u16* h1buf,
                                                 float* __restrict__ hfin,
                                                 unsigned* bar) {
  const int wg = blockIdx.x;
  const int tid = threadIdx.x;
  const int wave = tid >> 6, lane = tid & 63;
  const int nt = wg * 2 + (wave & 1);              // n-tile 0..127
  const int mg = wave >> 1;                        // 0..1 -> batches mg*32..mg*32+31
  const int b0 = mg * 32;
  const int arow = lane & 15;
  const int kloc = (lane >> 4) * 8;
  const int jj = (lane & 15) >> 2;
  const int gsel = lane & 3;
  const int jg = nt * 4 + jj;                      // this lane's hidden unit j
  const int bu0 = b0 + (lane >> 4) * 4 + gsel;     // this lane's batch (tile 0)
  const int bu1 = bu0 + 16;                        // tile 1
  const float4 bias4 = *reinterpret_cast<const float4*>(biasp + nt * 16 + jj * 4);
  float c0 = 0.f, c1 = 0.f;
  unsigned* cnt = bar;
  unsigned* flag = bar + 32;
  const u16* wbase = wp + (size_t)nt * 18 * 512 + lane * 8;

  for (int t = 0; t < TP; ++t) {
    const u16* hc = (t & 1) ? h1buf : h0buf;
    u16* hn = (t & 1) ? h0buf : h1buf;
    f32x4 acc0 = {0.f, 0.f, 0.f, 0.f}, acc1 = {0.f, 0.f, 0.f, 0.f};
    const u16* xt = seq + (size_t)t * 4096;
    #pragma unroll
    for (int kt = 0; kt < 2; ++kt) {               // K 0..63: conv features
      short8 bf = *reinterpret_cast<const short8*>(wbase + kt * 512);
      short8 a0 = *reinterpret_cast<const short8*>(xt + (b0 + arow) * 64 + kt * 32 + kloc);
      short8 a1 = *reinterpret_cast<const short8*>(xt + (b0 + 16 + arow) * 64 + kt * 32 + kloc);
      acc0 = __builtin_amdgcn_mfma_f32_16x16x32_bf16(a0, bf, acc0, 0, 0, 0);
      acc1 = __builtin_amdgcn_mfma_f32_16x16x32_bf16(a1, bf, acc1, 0, 0, 0);
    }
    #pragma unroll
    for (int kt = 2; kt < 18; ++kt) {              // K 64..575: recurrent h
      short8 bf = *reinterpret_cast<const short8*>(wbase + kt * 512);
      int joff = kt * 32 - 64 + kloc;
      short8 a0 = *reinterpret_cast<const short8*>(hc + (b0 + arow) * 512 + joff);
      short8 a1 = *reinterpret_cast<const short8*>(hc + (b0 + 16 + arow) * 512 + joff);
      acc0 = __builtin_amdgcn_mfma_f32_16x16x32_bf16(a0, bf, acc0, 0, 0, 0);
      acc1 = __builtin_amdgcn_mfma_f32_16x16x32_bf16(a1, bf, acc1, 0, 0, 0);
    }
    // gather i,f,g,o for this lane's unit from the 4 lanes holding cols 4j..4j+3
    float gv0[4], gv1[4];
    #pragma unroll
    for (int g = 0; g < 4; ++g) {
      int src = (lane & ~3) | g;
      #pragma unroll
      for (int r = 0; r < 4; ++r) {
        float v0 = __shfl(acc0[r], src);
        float v1 = __shfl(acc1[r], src);
        if (r == gsel) { gv0[g] = v0; gv1[g] = v1; }
      }
    }
    float i0 = sigmoidf_(gv0[0] + bias4.x);
    float f0 = sigmoidf_(gv0[1] + bias4.y);
    float g0 = tanhf_(gv0[2] + bias4.z);
    float o0 = sigmoidf_(gv0[3] + bias4.w);
    c0 = f0 * c0 + i0 * g0;
    float hv0 = o0 * tanhf_(c0);
    float i1 = sigmoidf_(gv1[0] + bias4.x);
    float f1 = sigmoidf_(gv1[1] + bias4.y);
    float g1 = tanhf_(gv1[2] + bias4.z);
    float o1 = sigmoidf_(gv1[3] + bias4.w);
    c1 = f1 * c1 + i1 * g1;
    float hv1 = o1 * tanhf_(c1);
    hn[bu0 * 512 + jg] = f2bf(hv0);
    hn[bu1 * 512 + jg] = f2bf(hv1);
    if (t == TP - 1) {
      hfin[bu0 * 512 + jg] = hv0;
      hfin[bu1 * 512 + jg] = hv1;
    }
    // ---- grid barrier (all 64 WGs co-resident; agent-scope fences for cross-XCD vis)
    __syncthreads();
    if (tid == 0) {
      __threadfence();
      unsigned old = __hip_atomic_fetch_add(cnt, 1u, __ATOMIC_ACQ_REL, __HIP_MEMORY_SCOPE_AGENT);
      if (old == NWG - 1) {
        __hip_atomic_store(cnt, 0u, __ATOMIC_RELAXED, __HIP_MEMORY_SCOPE_AGENT);
        __hip_atomic_store(flag, (unsigned)(t + 1), __ATOMIC_RELEASE, __HIP_MEMORY_SCOPE_AGENT);
      } else {
        while (__hip_atomic_load(flag, __ATOMIC_ACQUIRE, __HIP_MEMORY_SCOPE_AGENT) < (unsigned)(t + 1)) {
          __builtin_amdgcn_s_sleep(2);
        }
      }
      __threadfence();
    }
    __syncthreads();
  }
}

// ---- final linear: out[b][o] = h . lin_w[o] + lin_b[o]  (fp32)
__global__ void k_fc(const float* __restrict__ hfin, const float* __restrict__ lin_w,
                     const float* __restrict__ lin_b, float* __restrict__ out) {
  int b = blockIdx.x, o = threadIdx.x;             // 128 threads
  const float* hp = hfin + b * 512;
  const float* wq = lin_w + o * 512;
  float s = lin_b[o];
  #pragma unroll 4
  for (int j = 0; j < 512; ++j) s += hp[j] * wq[j];
  out[b * 128 + o] = s;
}

extern "C" void kernel_launch(void* const* d_in, const int* in_sizes, int n_in,
                              void* d_out, int out_size, void* d_ws, size_t ws_size,
                              hipStream_t stream) {
  const float* inX    = (const float*)d_in[0];
  const float* conv_w = (const float*)d_in[2];
  const float* conv_b = (const float*)d_in[3];
  const float* w_ih   = (const float*)d_in[4];
  const float* w_hh   = (const float*)d_in[5];
  const float* b_ih   = (const float*)d_in[6];
  const float* b_hh   = (const float*)d_in[7];
  const float* lin_w  = (const float*)d_in[8];
  const float* lin_b  = (const float*)d_in[9];
  float* out = (float*)d_out;
  char* ws = (char*)d_ws;
  u16*      wpack = (u16*)(ws + OFF_WPACK);
  u16*      seq   = (u16*)(ws + OFF_SEQ);
  float*    rnorm = (float*)(ws + OFF_RNORM);
  float*    biasp = (float*)(ws + OFF_BIAS);
  u16*      h0b   = (u16*)(ws + OFF_H0);
  u16*      h1b   = (u16*)(ws + OFF_H1);
  float*    hfin  = (float*)(ws + OFF_HFIN);
  unsigned* bar   = (unsigned*)(ws + OFF_BAR);

  k_init<<<dim3(128), dim3(256), 0, stream>>>(b_ih, b_hh, biasp, (unsigned*)(ws + OFF_H0), bar);
  k_pack<<<dim3(4608), dim3(256), 0, stream>>>(w_ih, w_hh, wpack);
  k_norm<<<dim3(16384), dim3(256), 0, stream>>>(inX, rnorm);
  k_conv<<<dim3(256, 64), dim3(256), 0, stream>>>(inX, rnorm, conv_w, conv_b, seq);
  k_lstm<<<dim3(NWG), dim3(256), 0, stream>>>(seq, wpack, biasp, h0b, h1b, hfin, bar);
  k_fc<<<dim3(64), dim3(128), 0, stream>>>(hfin, lin_w, lin_b, out);
}

// Round 3
// 9047.756 us; speedup vs baseline: 1.3015x; 1.3015x over previous
//
#include <hip/hip_runtime.h>

typedef __attribute__((ext_vector_type(8))) short short8;
typedef __attribute__((ext_vector_type(4))) float f32x4;
typedef unsigned short u16;

#define TP   1022      // conv output length = T-2
#define NWG  64        // workgroups in persistent LSTM kernel

// ws layout (byte offsets, all 256-aligned)
#define OFF_WPACK   0            // 2048*576*2   = 2359296
#define OFF_SEQ     2359296      // 1022*64*64*2 = 8372224
#define OFF_BIAS    10993664     // 2048*4       = 8192
#define OFF_H0      11001856     // 64*512*2     = 65536
#define OFF_H1      11067392     // 64*512*2     = 65536
#define OFF_HFIN    11132928     // 64*512*4     = 131072
#define OFF_BAR     11264000     // slots[64] @ +0, go @ +320B

#define FENCE_ACQ() __builtin_amdgcn_fence(__ATOMIC_ACQUIRE, "agent")
#define FENCE_REL() __builtin_amdgcn_fence(__ATOMIC_RELEASE, "agent")

__device__ inline u16 f2bf(float x) {
  union { float f; unsigned u; } un; un.f = x;
  unsigned r = un.u + 0x7fffu + ((un.u >> 16) & 1u);  // RNE
  return (u16)(r >> 16);
}
__device__ inline float sigmoidf_(float x) { return 1.f / (1.f + __expf(-x)); }
__device__ inline float tanhf_(float x)    { return 2.f / (1.f + __expf(-2.f * x)) - 1.f; }

// ---- init: zero h buffers + barrier slots, build packed bias (b_ih+b_hh, n=4j+g order)
__global__ void k_init(const float* __restrict__ b_ih, const float* __restrict__ b_hh,
                       float* __restrict__ biasp, unsigned* __restrict__ hzero,
                       unsigned* __restrict__ bar) {
  int tid = blockIdx.x * 256 + threadIdx.x;
  if (tid < 32768) hzero[tid] = 0u;                 // both h bufs (131072 B)
  if (tid < 2048) {
    int j = tid >> 2, g = tid & 3;
    int row = g * 512 + j;
    biasp[tid] = b_ih[row] + b_hh[row];
  }
  if (tid < 128) bar[tid] = 0u;                     // slots + go
}

// ---- pack W = [w_ih ; w_hh] (2048 x 576) into MFMA A-fragment order, bf16.
// packed gate-row n = 4*j + g.  per (mtile,ktile): lane holds row n0+(lane&15),
// k = k0 + (lane>>4)*8 + i, 8 contiguous bf16 per lane.
__global__ void k_pack(const float* __restrict__ w_ih, const float* __restrict__ w_hh,
                       u16* __restrict__ wp) {
  int idx = blockIdx.x * 256 + threadIdx.x;        // < 128*18*512 = 1179648
  int nt = idx / 9216;
  int rem = idx - nt * 9216;
  int kt = rem / 512;
  int rem2 = rem - kt * 512;
  int lane = rem2 >> 3, i = rem2 & 7;
  int n = nt * 16 + (lane & 15);
  int k = kt * 32 + (lane >> 4) * 8 + i;
  int j = n >> 2, g = n & 3;
  int row = g * 512 + j;
  float v = (k < 64) ? w_ih[row * 64 + k] : w_hh[row * 512 + (k - 64)];
  wp[idx] = f2bf(v);
}

// ---- normalize (fused) + conv1d(k=3, VALID) + relu -> seq[t][b][oc] bf16
__global__ __launch_bounds__(256) void k_conv(const float* __restrict__ inX,
                                              const float* __restrict__ conv_w,
                                              const float* __restrict__ conv_b,
                                              u16* __restrict__ seq) {
  __shared__ float xn[6][128];
  __shared__ float rn[6];
  int b = blockIdx.y;
  int t0 = blockIdx.x * 4;
  int tid = threadIdx.x;
  for (int e = tid; e < 768; e += 256) {
    int ri = e >> 7, col = e & 127;
    int t = t0 + ri;
    xn[ri][col] = (t < 1024) ? inX[((size_t)b * 1024 + t) * 128 + col] : 0.f;
  }
  __syncthreads();
  if (tid < 192) {                                 // 6 rows x 32 lanes
    int ri = tid >> 5, l32 = tid & 31;
    float4 v = *reinterpret_cast<const float4*>(&xn[ri][l32 * 4]);
    float s = v.x * v.x + v.y * v.y + v.z * v.z + v.w * v.w;
    #pragma unroll
    for (int d = 1; d < 32; d <<= 1) s += __shfl_xor(s, d, 32);
    if (l32 == 0) rn[ri] = 1.f / fmaxf(sqrtf(s), 1e-12f);
  }
  __syncthreads();
  for (int e = tid; e < 768; e += 256) {
    int ri = e >> 7, col = e & 127;
    xn[ri][col] *= rn[ri];
  }
  __syncthreads();
  int oc = tid & 63, ty = tid >> 6;
  int t = t0 + ty;
  if (t < TP) {
    const float* wr = conv_w + oc * 384;           // (OC, IN, 3) row-major
    float s = conv_b[oc];
    #pragma unroll 4
    for (int i = 0; i < 128; ++i) {
      s += wr[i * 3 + 0] * xn[ty + 0][i]
         + wr[i * 3 + 1] * xn[ty + 1][i]
         + wr[i * 3 + 2] * xn[ty + 2][i];
    }
    s = fmaxf(s, 0.f);
    seq[((size_t)t * 64 + b) * 64 + oc] = f2bf(s);
  }
}

// ---- persistent LSTM, operand-swapped: C = W(gate rows) x [x;h](batch cols).
// wave -> m-tile mt (16 gate rows = 4 units), 2 n-tiles (32 batches).
// Weights in VGPRs (18 x short8). All 4 gates of a unit land in one lane's acc[0..3].
__global__ __launch_bounds__(256, 1) void k_lstm(const u16* __restrict__ seq,
                                                 const u16* __restrict__ wp,
                                                 const float* __restrict__ biasp,
                                                 u16* h0buf, u16* h1buf,
                                                 float* __restrict__ hfin,
                                                 unsigned* bar) {
  const int wg = blockIdx.x;
  const int tid = threadIdx.x;
  const int wave = tid >> 6, lane = tid & 63;
  const int wgl = wg * 4 + wave;                   // 0..255
  const int mt = wgl >> 1;                         // 0..127 gate m-tile
  const int nh = wgl & 1;                          // batch half
  const int b0n = nh * 32 + (lane & 15);           // batch (n-tile 0)
  const int b1n = b0n + 16;                        // batch (n-tile 1)
  const int hi = lane >> 4;                        // 0..3
  const int koff = hi * 8;
  const int u = mt * 4 + hi;                       // this lane's hidden unit
  const float4 bias4 = *reinterpret_cast<const float4*>(biasp + mt * 16 + hi * 4);

  // preload this wave's weight slice into registers: 18 k-tiles x 8 bf16/lane
  short8 w[18];
  {
    const u16* wbase = wp + (size_t)mt * (18 * 512) + lane * 8;
    #pragma unroll
    for (int kt = 0; kt < 18; ++kt) w[kt] = *reinterpret_cast<const short8*>(wbase + kt * 512);
  }

  unsigned* slots = bar;
  unsigned* go = bar + 80;                          // separate cache line
  float c0 = 0.f, c1 = 0.f;
  f32x4 acc0, acc1;

#define XPART(T) do { \
    const u16* xt_ = seq + (size_t)(T) * 4096; \
    short8 x0a = *reinterpret_cast<const short8*>(xt_ + b0n * 64 + koff); \
    short8 x1a = *reinterpret_cast<const short8*>(xt_ + b1n * 64 + koff); \
    short8 x0b = *reinterpret_cast<const short8*>(xt_ + b0n * 64 + 32 + koff); \
    short8 x1b = *reinterpret_cast<const short8*>(xt_ + b1n * 64 + 32 + koff); \
    f32x4 z_ = {0.f, 0.f, 0.f, 0.f}; \
    acc0 = __builtin_amdgcn_mfma_f32_16x16x32_bf16(w[0], x0a, z_, 0, 0, 0); \
    acc1 = __builtin_amdgcn_mfma_f32_16x16x32_bf16(w[0], x1a, z_, 0, 0, 0); \
    acc0 = __builtin_amdgcn_mfma_f32_16x16x32_bf16(w[1], x0b, acc0, 0, 0, 0); \
    acc1 = __builtin_amdgcn_mfma_f32_16x16x32_bf16(w[1], x1b, acc1, 0, 0, 0); \
  } while (0)

  XPART(0);                                        // x-part for t=0 (h(-1)=0)

  for (int t = 0; t < TP; ++t) {
    // ---- wait for h(t-1) (skip t=0): relaxed polls, ONE acquire fence
    if (t > 0) {
      if (wg == 0) {
        if (wave == 0) {
          const unsigned tgt = (unsigned)t;
          for (;;) {
            unsigned v = __hip_atomic_load(&slots[lane], __ATOMIC_RELAXED, __HIP_MEMORY_SCOPE_AGENT);
            if (__all(v >= tgt)) break;
            __builtin_amdgcn_s_sleep(1);
          }
          if (lane == 0)
            __hip_atomic_store(go, tgt, __ATOMIC_RELAXED, __HIP_MEMORY_SCOPE_AGENT);
          FENCE_ACQ();
        }
      } else {
        if (tid == 0) {
          while (__hip_atomic_load(go, __ATOMIC_RELAXED, __HIP_MEMORY_SCOPE_AGENT) < (unsigned)t)
            __builtin_amdgcn_s_sleep(1);
          FENCE_ACQ();
        }
      }
      __syncthreads();
    }

    const u16* hc = (t & 1) ? h1buf : h0buf;
    u16* hn = (t & 1) ? h0buf : h1buf;

    // ---- recurrent part: 16 k-tiles over h(t-1)
    #pragma unroll
    for (int kt = 2; kt < 18; ++kt) {
      short8 hb0 = *reinterpret_cast<const short8*>(hc + b0n * 512 + (kt - 2) * 32 + koff);
      short8 hb1 = *reinterpret_cast<const short8*>(hc + b1n * 512 + (kt - 2) * 32 + koff);
      acc0 = __builtin_amdgcn_mfma_f32_16x16x32_bf16(w[kt], hb0, acc0, 0, 0, 0);
      acc1 = __builtin_amdgcn_mfma_f32_16x16x32_bf16(w[kt], hb1, acc1, 0, 0, 0);
    }

    // ---- gates (i,f,g,o all in this lane's acc[0..3])
    float i0 = sigmoidf_(acc0[0] + bias4.x);
    float f0 = sigmoidf_(acc0[1] + bias4.y);
    float g0 = tanhf_(acc0[2] + bias4.z);
    float o0 = sigmoidf_(acc0[3] + bias4.w);
    c0 = f0 * c0 + i0 * g0;
    float hv0 = o0 * tanhf_(c0);
    float i1 = sigmoidf_(acc1[0] + bias4.x);
    float f1 = sigmoidf_(acc1[1] + bias4.y);
    float g1 = tanhf_(acc1[2] + bias4.z);
    float o1 = sigmoidf_(acc1[3] + bias4.w);
    c1 = f1 * c1 + i1 * g1;
    float hv1 = o1 * tanhf_(c1);

    hn[b0n * 512 + u] = f2bf(hv0);
    hn[b1n * 512 + u] = f2bf(hv1);
    if (t == TP - 1) {
      hfin[b0n * 512 + u] = hv0;
      hfin[b1n * 512 + u] = hv1;
    }

    // ---- signal: drain stores (syncthreads), ONE release fence, slot store
    __syncthreads();
    if (tid == 0) {
      FENCE_REL();
      __hip_atomic_store(&slots[wg], (unsigned)(t + 1), __ATOMIC_RELAXED, __HIP_MEMORY_SCOPE_AGENT);
    }

    // ---- x-part prefetch for t+1 (independent of h) overlaps barrier latency
    if (t + 1 < TP) XPART(t + 1);
  }
#undef XPART
}

// ---- final linear: out[b][o] = h . lin_w[o] + lin_b[o]  (fp32)
__global__ void k_fc(const float* __restrict__ hfin, const float* __restrict__ lin_w,
                     const float* __restrict__ lin_b, float* __restrict__ out) {
  int b = blockIdx.x, o = threadIdx.x;             // 128 threads
  const float* hp = hfin + b * 512;
  const float* wq = lin_w + o * 512;
  float s = lin_b[o];
  #pragma unroll 4
  for (int j = 0; j < 512; ++j) s += hp[j] * wq[j];
  out[b * 128 + o] = s;
}

extern "C" void kernel_launch(void* const* d_in, const int* in_sizes, int n_in,
                              void* d_out, int out_size, void* d_ws, size_t ws_size,
                              hipStream_t stream) {
  const float* inX    = (const float*)d_in[0];
  const float* conv_w = (const float*)d_in[2];
  const float* conv_b = (const float*)d_in[3];
  const float* w_ih   = (const float*)d_in[4];
  const float* w_hh   = (const float*)d_in[5];
  const float* b_ih   = (const float*)d_in[6];
  const float* b_hh   = (const float*)d_in[7];
  const float* lin_w  = (const float*)d_in[8];
  const float* lin_b  = (const float*)d_in[9];
  float* out = (float*)d_out;
  char* ws = (char*)d_ws;
  u16*      wpack = (u16*)(ws + OFF_WPACK);
  u16*      seq   = (u16*)(ws + OFF_SEQ);
  float*    biasp = (float*)(ws + OFF_BIAS);
  u16*      h0b   = (u16*)(ws + OFF_H0);
  u16*      h1b   = (u16*)(ws + OFF_H1);
  float*    hfin  = (float*)(ws + OFF_HFIN);
  unsigned* bar   = (unsigned*)(ws + OFF_BAR);

  k_init<<<dim3(128), dim3(256), 0, stream>>>(b_ih, b_hh, biasp, (unsigned*)(ws + OFF_H0), bar);
  k_pack<<<dim3(4608), dim3(256), 0, stream>>>(w_ih, w_hh, wpack);
  k_conv<<<dim3(256, 64), dim3(256), 0, stream>>>(inX, conv_w, conv_b, seq);
  k_lstm<<<dim3(NWG), dim3(256), 0, stream>>>(seq, wpack, biasp, h0b, h1b, hfin, bar);
  k_fc<<<dim3(64), dim3(128), 0, stream>>>(hfin, lin_w, lin_b, out);
}